// Round 5
// baseline (411.862 us; speedup 1.0000x reference)
//
#include <hip/hip_runtime.h>

#define N_ 100000
#define E_ 600000
#define IND_ 128
#define OUTD_ 256
#define NT_ (N_/16)        // 6250 row-tiles of 16
#define NB_ 98             // scan blocks of 1024
#define CASTN_ (N_*IND_/2) // 6.4M u32 words of bf16 pairs

typedef __attribute__((ext_vector_type(8))) short bf16x8;
typedef __attribute__((ext_vector_type(4))) float f32x4;
typedef __attribute__((ext_vector_type(2))) unsigned int u32x2;

static __device__ __forceinline__ unsigned f2bf_u(float f){
  union { float f; unsigned u; } v; v.f = f;
  return (v.u + 0x7fffu + ((v.u >> 16) & 1u)) >> 16;   // RNE bf16
}
static __device__ __forceinline__ unsigned pack2(float a, float b){
  return f2bf_u(a) | (f2bf_u(b) << 16);
}
static __device__ __forceinline__ float blo(unsigned u){
  union { unsigned u; float f; } v; v.u = u << 16; return v.f;
}
static __device__ __forceinline__ float bhi(unsigned u){
  union { unsigned u; float f; } v; v.u = u & 0xffff0000u; return v.f;
}

// ---- weight prep (fp32 -> bf16 fragment order) + BN fold + x -> bf16 cast
__global__ void k_prep(const float* __restrict__ x,
                       const float* __restrict__ W1, const float* __restrict__ W2,
                       const float* __restrict__ Wp, const float* __restrict__ b2,
                       const float* __restrict__ gamma, const float* __restrict__ beta,
                       const float* __restrict__ mean, const float* __restrict__ var,
                       const float* __restrict__ bp,
                       unsigned short* __restrict__ W1s, unsigned short* __restrict__ W2s,
                       unsigned short* __restrict__ Wps,
                       float* __restrict__ scale, float* __restrict__ shift,
                       unsigned* __restrict__ xbw)
{
  int gid = blockIdx.x*256 + threadIdx.x;
  if (gid < 16384) {
    const float* W; unsigned short* Ws; int u;
    if (gid < 4096)       { W = W1; Ws = W1s; u = gid; }
    else if (gid < 12288) { W = W2; Ws = W2s; u = gid - 4096; }
    else                  { W = Wp; Ws = Wps; u = gid - 12288; }
    int l  = u & 63;
    int km = (u >> 6) & 1;
    int t  = (u >> 7) & 15;
    int q  = u >> 11;
    int kk = 2*q + km;
    int kb = kk*32 + (l >> 4)*8;
    int c  = 16*t + (l & 15);
    #pragma unroll
    for (int j = 0; j < 8; j++)
      Ws[u*8 + j] = (unsigned short)f2bf_u(W[(size_t)(kb + j)*OUTD_ + c]);
  } else if (gid < 16640) {
    int c = gid - 16384;
    float s = gamma[c] * rsqrtf(var[c] + 1e-5f);
    scale[c] = s;
    shift[c] = (b2[c] - mean[c]) * s + beta[c] + bp[c];
  } else if (gid < 16640 + CASTN_) {
    int ci = gid - 16640;
    float2 v = ((const float2*)x)[ci];
    xbw[ci] = pack2(v.x, v.y);
  }
}

__global__ void k_deg(const int* __restrict__ dst, int* __restrict__ deg){
  int e = blockIdx.x*256 + threadIdx.x;
  if (e < E_) atomicAdd(&deg[dst[e]], 1);
}

// hierarchical scan pass 1: per-1024-chunk sums
__global__ __launch_bounds__(1024) void k_scan1(const int* __restrict__ deg,
                                                int* __restrict__ bsum, int* __restrict__ offs){
  __shared__ int red[16];
  int tid = threadIdx.x;
  int i = blockIdx.x*1024 + tid;
  int v = (i < N_) ? deg[i] : 0;
  #pragma unroll
  for (int d = 32; d; d >>= 1) v += __shfl_down(v, d);
  if ((tid & 63) == 0) red[tid >> 6] = v;
  __syncthreads();
  if (tid < 16) {
    int s = red[tid];
    #pragma unroll
    for (int d = 8; d; d >>= 1) s += __shfl_down(s, d, 16);
    if (tid == 0) bsum[blockIdx.x] = s;
  }
  if (blockIdx.x == 0 && tid == 0) offs[N_] = E_;
}

// pass 2: each block redundantly scans the 98 block sums + its own chunk
__global__ __launch_bounds__(1024) void k_scan2(const int* __restrict__ deg,
                                                const int* __restrict__ bsum, int* __restrict__ offs){
  __shared__ int bs[128];
  __shared__ int d1[1024];
  int tid = threadIdx.x;
  if (tid < 128) bs[tid] = (tid < NB_) ? bsum[tid] : 0;
  __syncthreads();
  #pragma unroll
  for (int d = 1; d < 128; d <<= 1){
    int v = (tid < 128 && tid >= d) ? bs[tid - d] : 0;
    __syncthreads();
    if (tid < 128) bs[tid] += v;
    __syncthreads();
  }
  int bprefix = (blockIdx.x > 0) ? bs[blockIdx.x - 1] : 0;
  int i = blockIdx.x*1024 + tid;
  int v = (i < N_) ? deg[i] : 0;
  d1[tid] = v;
  __syncthreads();
  #pragma unroll
  for (int d = 1; d < 1024; d <<= 1){
    int t = (tid >= d) ? d1[tid - d] : 0;
    __syncthreads();
    d1[tid] += t;
    __syncthreads();
  }
  if (i < N_) offs[i] = bprefix + d1[tid] - v;
}

__global__ void k_fill(const int* __restrict__ src, const int* __restrict__ dst,
                       const int* __restrict__ offs, int* __restrict__ cur, int* __restrict__ adj){
  int e = blockIdx.x*256 + threadIdx.x;
  if (e < E_) {
    int d = dst[e];
    int p = atomicAdd(&cur[d], 1);
    adj[offs[d] + p] = src[e];
  }
}

// one wave per dst row, bf16 gather (256B/row, 1 dword/lane); 8 rows in flight
__global__ void k_agg(const unsigned* __restrict__ xb32, const int* __restrict__ offs,
                      const int* __restrict__ adj, const float* __restrict__ epsp,
                      unsigned* __restrict__ h0)
{
  int row  = blockIdx.x*4 + (threadIdx.x >> 6);
  int lane = threadIdx.x & 63;
  if (row >= N_) return;
  unsigned xw = xb32[(size_t)row*64 + lane];
  float ax0=0,ay0=0,ax1=0,ay1=0,ax2=0,ay2=0,ax3=0,ay3=0;
  float ax4=0,ay4=0,ax5=0,ay5=0,ax6=0,ay6=0,ax7=0,ay7=0;
  int b = offs[row], e = offs[row+1];
  for (int base = b; base < e; base += 64){
    int cnt = min(64, e - base);
    int idx = adj[base + min(lane, cnt - 1)];
    int j = 0;
    for (; j + 8 <= cnt; j += 8){
      int n0 = __shfl(idx, j+0), n1 = __shfl(idx, j+1);
      int n2 = __shfl(idx, j+2), n3 = __shfl(idx, j+3);
      int n4 = __shfl(idx, j+4), n5 = __shfl(idx, j+5);
      int n6 = __shfl(idx, j+6), n7 = __shfl(idx, j+7);
      unsigned v0 = xb32[(size_t)n0*64 + lane];
      unsigned v1 = xb32[(size_t)n1*64 + lane];
      unsigned v2 = xb32[(size_t)n2*64 + lane];
      unsigned v3 = xb32[(size_t)n3*64 + lane];
      unsigned v4 = xb32[(size_t)n4*64 + lane];
      unsigned v5 = xb32[(size_t)n5*64 + lane];
      unsigned v6 = xb32[(size_t)n6*64 + lane];
      unsigned v7 = xb32[(size_t)n7*64 + lane];
      ax0 += blo(v0); ay0 += bhi(v0);
      ax1 += blo(v1); ay1 += bhi(v1);
      ax2 += blo(v2); ay2 += bhi(v2);
      ax3 += blo(v3); ay3 += bhi(v3);
      ax4 += blo(v4); ay4 += bhi(v4);
      ax5 += blo(v5); ay5 += bhi(v5);
      ax6 += blo(v6); ay6 += bhi(v6);
      ax7 += blo(v7); ay7 += bhi(v7);
    }
    for (; j < cnt; j++){
      int n = __shfl(idx, j);
      unsigned v = xb32[(size_t)n*64 + lane];
      ax0 += blo(v); ay0 += bhi(v);
    }
  }
  float ax = ((ax0+ax1)+(ax2+ax3)) + ((ax4+ax5)+(ax6+ax7));
  float ay = ((ay0+ay1)+(ay2+ay3)) + ((ay4+ay5)+(ay6+ay7));
  float k1 = 1.f + epsp[0];
  h0[(size_t)row*64 + lane] = pack2(fmaf(k1, blo(xw), ax), fmaf(k1, bhi(xw), ay));
}

// persistent GEMM1, col-half: h1[:, half] = relu(h0 @ W1h + b1h). W1h resident in LDS.
// One sync after stage; tile loop is barrier-free (trans is wave-private).
__global__ __launch_bounds__(256, 3) void k_mlp1(const unsigned short* __restrict__ h0,
        const bf16x8* __restrict__ W1s, const float* __restrict__ b1,
        unsigned short* __restrict__ h1s)
{
  __shared__ bf16x8 w[2048];                        // 32KB W1 half
  __shared__ __align__(16) char trans[4][2][1280];  // per-wave 16x(64B+16B pad)
  int tid = threadIdx.x, wv = tid >> 6, lane = tid & 63, g = lane >> 4, r = lane & 15;
  int ch = blockIdx.x & 1;
  #pragma unroll
  for (int i = 0; i < 8; i++){
    int v = tid + i*256;
    int l = v & 63, p = v >> 6;
    int km = p & 1, s = p >> 1;
    int q = s >> 3, tl = s & 7;
    w[v] = W1s[q*2048 + ((8*ch + tl)*2 + km)*64 + l];
  }
  __syncthreads();

  const float4* b1v = (const float4*)b1;
  int wid = (blockIdx.x >> 1)*4 + wv;               // 384 blocks/half * 4 waves = 1536
  for (int tile = wid; tile < NT_; tile += 1536){
    const bf16x8* hrow = (const bf16x8*)(h0 + ((size_t)tile*16 + r)*IND_);
    bf16x8 B[4];
    #pragma unroll
    for (int kk = 0; kk < 4; kk++) B[kk] = hrow[kk*4 + g];
    f32x4 acc[8];
    #pragma unroll
    for (int t = 0; t < 8; t++) acc[t] = (f32x4){0.f,0.f,0.f,0.f};
    #pragma unroll
    for (int q = 0; q < 2; q++)
      #pragma unroll
      for (int km = 0; km < 2; km++){
        bf16x8 Bf = B[2*q + km];
        #pragma unroll
        for (int tl = 0; tl < 8; tl++)
          acc[tl] = __builtin_amdgcn_mfma_f32_16x16x32_bf16(w[((q*8+tl)*2+km)*64 + lane], Bf, acc[tl], 0,0,0);
      }
    unsigned short* outp = h1s + (size_t)tile*4096;
    #pragma unroll
    for (int kkhl = 0; kkhl < 4; kkhl++){
      char* tr = &trans[wv][kkhl & 1][0];
      #pragma unroll
      for (int h = 0; h < 2; h++){
        int tl = 2*kkhl + h;
        float4 bb = b1v[(8*ch + tl)*4 + g];
        f32x4 a = acc[tl];
        float v0 = fmaxf(a.x + bb.x, 0.f);
        float v1 = fmaxf(a.y + bb.y, 0.f);
        float v2 = fmaxf(a.z + bb.z, 0.f);
        float v3 = fmaxf(a.w + bb.w, 0.f);
        u32x2 dd; dd.x = pack2(v0, v1); dd.y = pack2(v2, v3);
        *(u32x2*)(tr + r*80 + h*32 + g*8) = dd;
      }
      bf16x8 frag = *(const bf16x8*)(tr + r*80 + g*16);
      *(bf16x8*)(outp + ((ch*4 + kkhl)*64 + lane)*8) = frag;
    }
  }
}

// persistent GEMM2+proj, col-half: out[:, half] = BN(h1 @ W2h) + x @ Wph.
// W2h (64KB) resident in LDS; Wph resident in 128 VGPRs. Barrier-free tile loop.
__global__ __launch_bounds__(512, 2) void k_mlp2(const bf16x8* __restrict__ h1s,
        const unsigned short* __restrict__ xb16,
        const bf16x8* __restrict__ W2s, const bf16x8* __restrict__ Wps,
        const float* __restrict__ scale, const float* __restrict__ shift,
        float* __restrict__ out)
{
  __shared__ bf16x8 w[4096];   // 64KB W2 half
  int tid = threadIdx.x, wv = tid >> 6, lane = tid & 63, g = lane >> 4, r = lane & 15;
  int ch = blockIdx.x & 1;
  #pragma unroll
  for (int i = 0; i < 8; i++){
    int v = tid + i*512;
    int l = v & 63, p = v >> 6;
    int km = p & 1, s = p >> 1;
    int q = s >> 3, tl = s & 7;
    w[v] = W2s[q*2048 + ((8*ch + tl)*2 + km)*64 + l];
  }
  bf16x8 wp[2][2][8];
  #pragma unroll
  for (int q = 0; q < 2; q++)
    #pragma unroll
    for (int km = 0; km < 2; km++)
      #pragma unroll
      for (int tl = 0; tl < 8; tl++)
        wp[q][km][tl] = Wps[q*2048 + ((8*ch + tl)*2 + km)*64 + lane];
  __syncthreads();

  const float4* sc = (const float4*)scale;
  const float4* sh = (const float4*)shift;
  int wid = (blockIdx.x >> 1)*8 + wv;               // 128 blocks/half * 8 waves = 1024
  for (int tile = wid; tile < NT_; tile += 1024){
    const bf16x8* h1f = h1s + (size_t)tile*512;
    const bf16x8* xrowf = (const bf16x8*)(xb16 + ((size_t)tile*16 + r)*IND_);
    bf16x8 HF[8], XF[4];
    #pragma unroll
    for (int kk = 0; kk < 8; kk++) HF[kk] = h1f[kk*64 + lane];
    #pragma unroll
    for (int kk = 0; kk < 4; kk++) XF[kk] = xrowf[kk*4 + g];
    f32x4 acc[8];
    #pragma unroll
    for (int t = 0; t < 8; t++) acc[t] = (f32x4){0.f,0.f,0.f,0.f};
    #pragma unroll
    for (int q = 0; q < 4; q++)
      #pragma unroll
      for (int km = 0; km < 2; km++){
        bf16x8 Bf = HF[2*q + km];
        #pragma unroll
        for (int tl = 0; tl < 8; tl++)
          acc[tl] = __builtin_amdgcn_mfma_f32_16x16x32_bf16(w[((q*8+tl)*2+km)*64 + lane], Bf, acc[tl], 0,0,0);
      }
    #pragma unroll
    for (int q = 0; q < 2; q++)
      #pragma unroll
      for (int km = 0; km < 2; km++){
        bf16x8 Bf = XF[2*q + km];
        #pragma unroll
        for (int tl = 0; tl < 8; tl++)
          acc[tl] = __builtin_amdgcn_mfma_f32_16x16x32_bf16(wp[q][km][tl], Bf, acc[tl], 0,0,0);
      }
    #pragma unroll
    for (int tl = 0; tl < 8; tl++){
      int cb = (8*ch + tl)*4 + g;
      float4 s = sc[cb], b = sh[cb];
      f32x4 a = acc[tl];
      float4 o;
      o.x = fmaf(a.x, s.x, b.x);
      o.y = fmaf(a.y, s.y, b.y);
      o.z = fmaf(a.z, s.z, b.z);
      o.w = fmaf(a.w, s.w, b.w);
      *(float4*)(out + ((size_t)tile*16 + r)*OUTD_ + (8*ch+tl)*16 + g*4) = o;
    }
  }
}

extern "C" void kernel_launch(void* const* d_in, const int* in_sizes, int n_in,
                              void* d_out, int out_size, void* d_ws, size_t ws_size,
                              hipStream_t stream)
{
  const float* x     = (const float*)d_in[0];
  const int*   ei    = (const int*)d_in[1];     // [2][E]: src then dst
  const float* eps   = (const float*)d_in[2];
  const float* W1    = (const float*)d_in[3];
  const float* b1    = (const float*)d_in[4];
  const float* W2    = (const float*)d_in[5];
  const float* b2    = (const float*)d_in[6];
  const float* gamma = (const float*)d_in[7];
  const float* beta  = (const float*)d_in[8];
  const float* rmean = (const float*)d_in[9];
  const float* rvar  = (const float*)d_in[10];
  const float* Wp    = (const float*)d_in[11];
  const float* bp    = (const float*)d_in[12];
  float* out = (float*)d_out;

  char* ws = (char*)d_ws; size_t off = 0;
  auto carve = [&](size_t b)->char* { char* p = ws + off; off = (off + b + 255) & ~(size_t)255; return p; };
  unsigned*       xbuf  = (unsigned*)carve((size_t)CASTN_*4);   // x as bf16 pairs
  unsigned*       h0    = (unsigned*)carve((size_t)N_*64*4);    // h0 as bf16 pairs
  unsigned short* h1s   = (unsigned short*)carve((size_t)N_*OUTD_*2);
  unsigned short* W1s   = (unsigned short*)carve(4096*16);
  unsigned short* W2s   = (unsigned short*)carve(8192*16);
  unsigned short* Wps   = (unsigned short*)carve(4096*16);
  float*          scale = (float*)carve(256*4);
  float*          shift = (float*)carve(256*4);
  int*            deg   = (int*)carve((size_t)N_*4);
  int*            cur   = (int*)carve((size_t)N_*4);
  int*            offs  = (int*)carve((size_t)(N_+1)*4);
  int*            adj   = (int*)carve((size_t)E_*4);
  int*            bsum  = (int*)carve((size_t)NB_*4);

  hipMemsetAsync(deg, 0, (size_t)N_*4, stream);
  hipMemsetAsync(cur, 0, (size_t)N_*4, stream);

  k_prep <<<(16640 + CASTN_ + 255)/256, 256, 0, stream>>>(x, W1, W2, Wp, b2, gamma, beta,
                                  rmean, rvar, bp, W1s, W2s, Wps, scale, shift, xbuf);
  k_deg  <<<(E_+255)/256, 256, 0, stream>>>(ei + E_, deg);
  k_scan1<<<NB_, 1024, 0, stream>>>(deg, bsum, offs);
  k_scan2<<<NB_, 1024, 0, stream>>>(deg, bsum, offs);
  k_fill <<<(E_+255)/256, 256, 0, stream>>>(ei, ei + E_, offs, cur, adj);
  k_agg  <<<(N_+3)/4, 256, 0, stream>>>(xbuf, offs, adj, eps, h0);
  k_mlp1 <<<768, 256, 0, stream>>>((const unsigned short*)h0, (const bf16x8*)W1s, b1, h1s);
  k_mlp2 <<<256, 512, 0, stream>>>((const bf16x8*)h1s, (const unsigned short*)xbuf,
                                   (const bf16x8*)W2s, (const bf16x8*)Wps, scale, shift, out);
}

// Round 6
// 209.878 us; speedup vs baseline: 1.9624x; 1.9624x over previous
//
#include <hip/hip_runtime.h>

#define N_ 100000
#define E_ 600000
#define IND_ 128
#define OUTD_ 256
#define NT_ (N_/16)        // 6250 row-tiles of 16
#define NB_ 98             // scan blocks of 1024
#define CASTN_ (N_*IND_/2) // 6.4M u32 words of bf16 pairs

typedef __attribute__((ext_vector_type(8))) short bf16x8;
typedef __attribute__((ext_vector_type(4))) float f32x4;
typedef __attribute__((ext_vector_type(2))) unsigned int u32x2;

static __device__ __forceinline__ unsigned f2bf_u(float f){
  union { float f; unsigned u; } v; v.f = f;
  return (v.u + 0x7fffu + ((v.u >> 16) & 1u)) >> 16;   // RNE bf16
}
static __device__ __forceinline__ unsigned pack2(float a, float b){
  return f2bf_u(a) | (f2bf_u(b) << 16);
}
static __device__ __forceinline__ float blo(unsigned u){
  union { unsigned u; float f; } v; v.u = u << 16; return v.f;
}
static __device__ __forceinline__ float bhi(unsigned u){
  union { unsigned u; float f; } v; v.u = u & 0xffff0000u; return v.f;
}

// ---- weight prep (fp32 -> bf16 fragment order) + BN fold + x -> bf16 cast + degree count
__global__ void k_prep(const float* __restrict__ x,
                       const float* __restrict__ W1, const float* __restrict__ W2,
                       const float* __restrict__ Wp, const float* __restrict__ b2,
                       const float* __restrict__ gamma, const float* __restrict__ beta,
                       const float* __restrict__ mean, const float* __restrict__ var,
                       const float* __restrict__ bp,
                       const int* __restrict__ dst, int* __restrict__ deg,
                       unsigned short* __restrict__ W1s, unsigned short* __restrict__ W2s,
                       unsigned short* __restrict__ Wps,
                       float* __restrict__ scale, float* __restrict__ shift,
                       unsigned* __restrict__ xbw)
{
  int gid = blockIdx.x*256 + threadIdx.x;
  if (gid < 16384) {
    const float* W; unsigned short* Ws; int u;
    if (gid < 4096)       { W = W1; Ws = W1s; u = gid; }
    else if (gid < 12288) { W = W2; Ws = W2s; u = gid - 4096; }
    else                  { W = Wp; Ws = Wps; u = gid - 12288; }
    int l  = u & 63;
    int km = (u >> 6) & 1;
    int t  = (u >> 7) & 15;
    int q  = u >> 11;
    int kk = 2*q + km;
    int kb = kk*32 + (l >> 4)*8;
    int c  = 16*t + (l & 15);
    #pragma unroll
    for (int j = 0; j < 8; j++)
      Ws[u*8 + j] = (unsigned short)f2bf_u(W[(size_t)(kb + j)*OUTD_ + c]);
  } else if (gid < 16640) {
    int c = gid - 16384;
    float s = gamma[c] * rsqrtf(var[c] + 1e-5f);
    scale[c] = s;
    shift[c] = (b2[c] - mean[c]) * s + beta[c] + bp[c];
  } else if (gid < 16640 + CASTN_) {
    int ci = gid - 16640;
    float2 v = ((const float2*)x)[ci];
    xbw[ci] = pack2(v.x, v.y);
  } else if (gid < 16640 + CASTN_ + E_) {
    int e = gid - 16640 - CASTN_;
    atomicAdd(&deg[dst[e]], 1);
  }
}

// hierarchical scan pass 1: per-1024-chunk sums
__global__ __launch_bounds__(1024) void k_scan1(const int* __restrict__ deg,
                                                int* __restrict__ bsum, int* __restrict__ offs){
  __shared__ int red[16];
  int tid = threadIdx.x;
  int i = blockIdx.x*1024 + tid;
  int v = (i < N_) ? deg[i] : 0;
  #pragma unroll
  for (int d = 32; d; d >>= 1) v += __shfl_down(v, d);
  if ((tid & 63) == 0) red[tid >> 6] = v;
  __syncthreads();
  if (tid < 16) {
    int s = red[tid];
    #pragma unroll
    for (int d = 8; d; d >>= 1) s += __shfl_down(s, d, 16);
    if (tid == 0) bsum[blockIdx.x] = s;
  }
  if (blockIdx.x == 0 && tid == 0) offs[N_] = E_;
}

// pass 2: each block redundantly scans the 98 block sums + its own chunk
__global__ __launch_bounds__(1024) void k_scan2(const int* __restrict__ deg,
                                                const int* __restrict__ bsum, int* __restrict__ offs){
  __shared__ int bs[128];
  __shared__ int d1[1024];
  int tid = threadIdx.x;
  if (tid < 128) bs[tid] = (tid < NB_) ? bsum[tid] : 0;
  __syncthreads();
  #pragma unroll
  for (int d = 1; d < 128; d <<= 1){
    int v = (tid < 128 && tid >= d) ? bs[tid - d] : 0;
    __syncthreads();
    if (tid < 128) bs[tid] += v;
    __syncthreads();
  }
  int bprefix = (blockIdx.x > 0) ? bs[blockIdx.x - 1] : 0;
  int i = blockIdx.x*1024 + tid;
  int v = (i < N_) ? deg[i] : 0;
  d1[tid] = v;
  __syncthreads();
  #pragma unroll
  for (int d = 1; d < 1024; d <<= 1){
    int t = (tid >= d) ? d1[tid - d] : 0;
    __syncthreads();
    d1[tid] += t;
    __syncthreads();
  }
  if (i < N_) offs[i] = bprefix + d1[tid] - v;
}

__global__ void k_fill(const int* __restrict__ src, const int* __restrict__ dst,
                       const int* __restrict__ offs, int* __restrict__ cur, int* __restrict__ adj){
  int e = blockIdx.x*256 + threadIdx.x;
  if (e < E_) {
    int d = dst[e];
    int p = atomicAdd(&cur[d], 1);
    adj[offs[d] + p] = src[e];
  }
}

// one wave per dst row, bf16 gather (256B/row, 1 dword/lane); 8 rows in flight
__global__ void k_agg(const unsigned* __restrict__ xb32, const int* __restrict__ offs,
                      const int* __restrict__ adj, const float* __restrict__ epsp,
                      unsigned* __restrict__ h0)
{
  int row  = blockIdx.x*4 + (threadIdx.x >> 6);
  int lane = threadIdx.x & 63;
  if (row >= N_) return;
  unsigned xw = xb32[(size_t)row*64 + lane];
  float ax0=0,ay0=0,ax1=0,ay1=0,ax2=0,ay2=0,ax3=0,ay3=0;
  float ax4=0,ay4=0,ax5=0,ay5=0,ax6=0,ay6=0,ax7=0,ay7=0;
  int b = offs[row], e = offs[row+1];
  for (int base = b; base < e; base += 64){
    int cnt = min(64, e - base);
    int idx = adj[base + min(lane, cnt - 1)];
    int j = 0;
    for (; j + 8 <= cnt; j += 8){
      int n0 = __shfl(idx, j+0), n1 = __shfl(idx, j+1);
      int n2 = __shfl(idx, j+2), n3 = __shfl(idx, j+3);
      int n4 = __shfl(idx, j+4), n5 = __shfl(idx, j+5);
      int n6 = __shfl(idx, j+6), n7 = __shfl(idx, j+7);
      unsigned v0 = xb32[(size_t)n0*64 + lane];
      unsigned v1 = xb32[(size_t)n1*64 + lane];
      unsigned v2 = xb32[(size_t)n2*64 + lane];
      unsigned v3 = xb32[(size_t)n3*64 + lane];
      unsigned v4 = xb32[(size_t)n4*64 + lane];
      unsigned v5 = xb32[(size_t)n5*64 + lane];
      unsigned v6 = xb32[(size_t)n6*64 + lane];
      unsigned v7 = xb32[(size_t)n7*64 + lane];
      ax0 += blo(v0); ay0 += bhi(v0);
      ax1 += blo(v1); ay1 += bhi(v1);
      ax2 += blo(v2); ay2 += bhi(v2);
      ax3 += blo(v3); ay3 += bhi(v3);
      ax4 += blo(v4); ay4 += bhi(v4);
      ax5 += blo(v5); ay5 += bhi(v5);
      ax6 += blo(v6); ay6 += bhi(v6);
      ax7 += blo(v7); ay7 += bhi(v7);
    }
    for (; j < cnt; j++){
      int n = __shfl(idx, j);
      unsigned v = xb32[(size_t)n*64 + lane];
      ax0 += blo(v); ay0 += bhi(v);
    }
  }
  float ax = ((ax0+ax1)+(ax2+ax3)) + ((ax4+ax5)+(ax6+ax7));
  float ay = ((ay0+ay1)+(ay2+ay3)) + ((ay4+ay5)+(ay6+ay7));
  float k1 = 1.f + epsp[0];
  h0[(size_t)row*64 + lane] = pack2(fmaf(k1, blo(xw), ax), fmaf(k1, bhi(xw), ay));
}

// GEMM1: h1 = relu(h0 @ W1 + b1), swapped-operand MFMA; h1 written in B-fragment order
__global__ __launch_bounds__(256) void k_mlp1(const unsigned short* __restrict__ h0,
        const bf16x8* __restrict__ W1s, const float* __restrict__ b1,
        unsigned short* __restrict__ h1s)
{
  __shared__ bf16x8 w[2048];                       // 32KB weight chunk
  __shared__ __align__(16) char trans[4][2][1280]; // per-wave 16x(64B+16B pad)
  int tid = threadIdx.x;
  int wv = tid >> 6, lane = tid & 63, g = lane >> 4, r = lane & 15;
  int tile0 = blockIdx.x*4 + wv;
  int tile  = min(tile0, NT_ - 1);

  const bf16x8* hrow = (const bf16x8*)(h0 + ((size_t)tile*16 + r)*IND_);
  bf16x8 B[4];
  #pragma unroll
  for (int kk = 0; kk < 4; kk++) B[kk] = hrow[kk*4 + g];

  f32x4 acc[16];
  #pragma unroll
  for (int t = 0; t < 16; t++) acc[t] = (f32x4){0.f,0.f,0.f,0.f};

  for (int q = 0; q < 2; q++){
    __syncthreads();
    #pragma unroll
    for (int i = 0; i < 8; i++) w[tid + i*256] = W1s[q*2048 + tid + i*256];
    __syncthreads();
    #pragma unroll
    for (int km = 0; km < 2; km++){
      bf16x8 Bf = B[2*q + km];
      #pragma unroll
      for (int t = 0; t < 16; t++)
        acc[t] = __builtin_amdgcn_mfma_f32_16x16x32_bf16(w[(t*2+km)*64 + lane], Bf, acc[t], 0,0,0);
    }
  }

  // epilogue: bias+relu -> bf16, per-32-col LDS regroup, coalesced frag-order store
  const float4* b1v = (const float4*)b1;
  unsigned short* outp = h1s + (size_t)tile*4096;
  bool act = (tile0 < NT_);
  #pragma unroll
  for (int kkh = 0; kkh < 8; kkh++){
    char* tr = &trans[wv][kkh & 1][0];
    #pragma unroll
    for (int h = 0; h < 2; h++){
      int t = 2*kkh + h;
      float4 bb = b1v[t*4 + g];
      f32x4 a = acc[t];
      float v0 = fmaxf(a.x + bb.x, 0.f);
      float v1 = fmaxf(a.y + bb.y, 0.f);
      float v2 = fmaxf(a.z + bb.z, 0.f);
      float v3 = fmaxf(a.w + bb.w, 0.f);
      u32x2 dd; dd.x = pack2(v0, v1); dd.y = pack2(v2, v3);
      *(u32x2*)(tr + r*80 + h*32 + g*8) = dd;
    }
    bf16x8 frag = *(const bf16x8*)(tr + r*80 + g*16);
    if (act) *(bf16x8*)(outp + (kkh*64 + lane)*8) = frag;
  }
}

// GEMM2+proj: out = (h1 @ W2) * scale + shift + x @ Wp  (swapped-operand, same acc)
__global__ __launch_bounds__(256) void k_mlp2(const bf16x8* __restrict__ h1s,
        const unsigned short* __restrict__ xb16,
        const bf16x8* __restrict__ W2s, const bf16x8* __restrict__ Wps,
        const float* __restrict__ scale, const float* __restrict__ shift,
        float* __restrict__ out)
{
  __shared__ bf16x8 w[2048];   // 32KB weight chunk
  int tid = threadIdx.x, wv = tid >> 6, lane = tid & 63, g = lane >> 4, r = lane & 15;
  int tile0 = blockIdx.x*4 + wv;
  int tile  = min(tile0, NT_ - 1);
  const bf16x8* h1f  = h1s + (size_t)tile*512;
  const bf16x8* xrow = (const bf16x8*)(xb16 + ((size_t)tile*16 + r)*IND_);

  f32x4 acc[16];
  #pragma unroll
  for (int t = 0; t < 16; t++) acc[t] = (f32x4){0.f,0.f,0.f,0.f};

  for (int q = 0; q < 4; q++){                       // K=256 of W2 in 4 chunks
    __syncthreads();
    #pragma unroll
    for (int i = 0; i < 8; i++) w[tid + i*256] = W2s[q*2048 + tid + i*256];
    __syncthreads();
    #pragma unroll
    for (int km = 0; km < 2; km++){
      bf16x8 Bf = h1f[(2*q + km)*64 + lane];
      #pragma unroll
      for (int t = 0; t < 16; t++)
        acc[t] = __builtin_amdgcn_mfma_f32_16x16x32_bf16(w[(t*2+km)*64 + lane], Bf, acc[t], 0,0,0);
    }
  }
  for (int q = 0; q < 2; q++){                       // K=128 of Wp in 2 chunks
    __syncthreads();
    #pragma unroll
    for (int i = 0; i < 8; i++) w[tid + i*256] = Wps[q*2048 + tid + i*256];
    __syncthreads();
    #pragma unroll
    for (int km = 0; km < 2; km++){
      bf16x8 Bf = xrow[(2*q + km)*4 + g];
      #pragma unroll
      for (int t = 0; t < 16; t++)
        acc[t] = __builtin_amdgcn_mfma_f32_16x16x32_bf16(w[(t*2+km)*64 + lane], Bf, acc[t], 0,0,0);
    }
  }

  if (tile0 < NT_){
    const float4* sc = (const float4*)scale;
    const float4* sh = (const float4*)shift;
    #pragma unroll
    for (int t = 0; t < 16; t++){
      float4 s = sc[t*4 + g], b = sh[t*4 + g];
      f32x4 a = acc[t];
      float4 o;
      o.x = fmaf(a.x, s.x, b.x);
      o.y = fmaf(a.y, s.y, b.y);
      o.z = fmaf(a.z, s.z, b.z);
      o.w = fmaf(a.w, s.w, b.w);
      *(float4*)(out + ((size_t)tile*16 + r)*OUTD_ + t*16 + g*4) = o;
    }
  }
}

extern "C" void kernel_launch(void* const* d_in, const int* in_sizes, int n_in,
                              void* d_out, int out_size, void* d_ws, size_t ws_size,
                              hipStream_t stream)
{
  const float* x     = (const float*)d_in[0];
  const int*   ei    = (const int*)d_in[1];     // [2][E]: src then dst
  const float* eps   = (const float*)d_in[2];
  const float* W1    = (const float*)d_in[3];
  const float* b1    = (const float*)d_in[4];
  const float* W2    = (const float*)d_in[5];
  const float* b2    = (const float*)d_in[6];
  const float* gamma = (const float*)d_in[7];
  const float* beta  = (const float*)d_in[8];
  const float* rmean = (const float*)d_in[9];
  const float* rvar  = (const float*)d_in[10];
  const float* Wp    = (const float*)d_in[11];
  const float* bp    = (const float*)d_in[12];
  float* out = (float*)d_out;

  char* ws = (char*)d_ws; size_t off = 0;
  auto carve = [&](size_t b)->char* { char* p = ws + off; off = (off + b + 255) & ~(size_t)255; return p; };
  unsigned*       xbuf  = (unsigned*)carve((size_t)CASTN_*4);   // x as bf16 pairs
  unsigned*       h0    = (unsigned*)carve((size_t)N_*64*4);    // h0 as bf16 pairs
  unsigned short* h1s   = (unsigned short*)carve((size_t)N_*OUTD_*2);
  unsigned short* W1s   = (unsigned short*)carve(4096*16);
  unsigned short* W2s   = (unsigned short*)carve(8192*16);
  unsigned short* Wps   = (unsigned short*)carve(4096*16);
  float*          scale = (float*)carve(256*4);
  float*          shift = (float*)carve(256*4);
  int*            deg   = (int*)carve((size_t)N_*4);
  int*            cur   = (int*)carve((size_t)N_*4);
  int*            offs  = (int*)carve((size_t)(N_+1)*4);
  int*            adj   = (int*)carve((size_t)E_*4);
  int*            bsum  = (int*)carve((size_t)NB_*4);

  hipMemsetAsync(deg, 0, (size_t)N_*4, stream);
  hipMemsetAsync(cur, 0, (size_t)N_*4, stream);

  k_prep <<<(16640 + CASTN_ + E_ + 255)/256, 256, 0, stream>>>(x, W1, W2, Wp, b2, gamma, beta,
                                  rmean, rvar, bp, ei + E_, deg,
                                  W1s, W2s, Wps, scale, shift, xbuf);
  k_scan1<<<NB_, 1024, 0, stream>>>(deg, bsum, offs);
  k_scan2<<<NB_, 1024, 0, stream>>>(deg, bsum, offs);
  k_fill <<<(E_+255)/256, 256, 0, stream>>>(ei, ei + E_, offs, cur, adj);
  k_agg  <<<(N_+3)/4, 256, 0, stream>>>(xbuf, offs, adj, eps, h0);
  k_mlp1 <<<(NT_+3)/4, 256, 0, stream>>>((const unsigned short*)h0, (const bf16x8*)W1s, b1, h1s);
  k_mlp2 <<<(NT_+3)/4, 256, 0, stream>>>((const bf16x8*)h1s, (const unsigned short*)xbuf,
                                         (const bf16x8*)W2s, (const bf16x8*)Wps, scale, shift, out);
}